// Round 2
// baseline (720.968 us; speedup 1.0000x reference)
//
#include <hip/hip_runtime.h>
#include <math.h>

// ---------------- problem constants ----------------
namespace {
constexpr int B_   = 2;
constexpr int NCAM = 6;
constexpr int BN   = 12;
constexpr int CIN  = 256;
constexpr int COUT = 80;
constexpr int DBIN = 16;
constexpr int NOUT = 96;            // DBIN + COUT
constexpr int HF = 32, WF = 88;
constexpr int HW = HF * WF;         // 2816
constexpr int BEVH = 128, BEVW = 128;
constexpr int NUMC = B_ * BEVH * BEVW;   // 32768
constexpr int NPTS = BN * DBIN * HW;     // 540672

// ws layout (byte offsets)
constexpr size_t MATS_OFF   = 0;                          // 12*24 floats   = 1152
constexpr size_t WT_OFF     = 2048;                       // 24576 f32     = 98304
constexpr size_t YT_OFF     = WT_OFF + 98304;             // 12*2816*96 f32 = 12976128
constexpr size_t CELL_OFF   = YT_OFF + 12976128;          // NPTS i32      = 2162688
constexpr size_t COUNTS_OFF = CELL_OFF + 2162688;         // NUMC i32      = 131072
constexpr size_t STARTS_OFF = COUNTS_OFF + 131072;
constexpr size_t CURS_OFF   = STARTS_OFF + 131072;
constexpr size_t PLIST_OFF  = CURS_OFF + 131072;          // NPTS i32
constexpr size_t BEV_OFF    = PLIST_OFF + 2162688;        // 2*80*128*128 f32 = 10485760
}

// ---------------- f32 LU inverse, LAPACK gesv-style (getrf + trsm column order) ----
template<int NM>
__device__ void inv_lu_f32(float* A, float* Y) {
    int piv[NM];
    // getrf2, right-looking, partial pivot, reciprocal column scale (sscal style)
    for (int j = 0; j < NM; j++) {
        int p = j; float mx = fabsf(A[j*NM+j]);
        for (int i = j+1; i < NM; i++) { float v = fabsf(A[i*NM+j]); if (v > mx) { mx = v; p = i; } }
        piv[j] = p;
        if (p != j) for (int k = 0; k < NM; k++) { float t = A[j*NM+k]; A[j*NM+k] = A[p*NM+k]; A[p*NM+k] = t; }
        float r = __frcp_rn(1.0f) / A[j*NM+j];                 // plain f32 divide
        r = __fdiv_rn(1.0f, A[j*NM+j]);
        for (int i = j+1; i < NM; i++) A[i*NM+j] = __fmul_rn(A[i*NM+j], r);
        for (int i = j+1; i < NM; i++) {
            float lij = A[i*NM+j];
            for (int k = j+1; k < NM; k++)
                A[i*NM+k] = __fsub_rn(A[i*NM+k], __fmul_rn(lij, A[j*NM+k]));
        }
    }
    // solve A X = I column by column (getrs: P, L-forward, U-back; BLAS column order)
    for (int c = 0; c < NM; c++) {
        float x[NM];
        for (int i = 0; i < NM; i++) x[i] = 0.f;
        x[c] = 1.f;
        for (int j = 0; j < NM; j++) { int p = piv[j]; if (p != j) { float t = x[j]; x[j] = x[p]; x[p] = t; } }
        for (int k = 0; k < NM; k++) {
            float xk = x[k];
            for (int i = k+1; i < NM; i++) x[i] = __fsub_rn(x[i], __fmul_rn(xk, A[i*NM+k]));
        }
        for (int k = NM-1; k >= 0; k--) {
            float xk = __fdiv_rn(x[k], A[k*NM+k]);
            x[k] = xk;
            for (int i = 0; i < k; i++) x[i] = __fsub_rn(x[i], __fmul_rn(xk, A[i*NM+k]));
        }
        for (int i = 0; i < NM; i++) Y[i*NM+c] = x[i];
    }
}

// ---------------- 1. precompute per-camera transforms (f32, reference semantics) ----
// layout per cam (24 f32): [0..8] invR(aug rot), [9..11] t_aug, [12..20] inv_l2i[:3,:3], [21..23] inv_l2i[:3,3]
__global__ void lss_prep_kernel(const float* __restrict__ l2i,
                                const float* __restrict__ aug,
                                float* __restrict__ mats) {
    int n = threadIdx.x;
    if (n >= BN) return;
    float A[16], IA[16];
    for (int i = 0; i < 16; i++) A[i] = l2i[n*16 + i];
    inv_lu_f32<4>(A, IA);
    float R[9], IR[9];
    for (int i = 0; i < 3; i++)
        for (int j = 0; j < 3; j++) R[i*3+j] = aug[n*16 + i*4 + j];
    inv_lu_f32<3>(R, IR);
    float* o = mats + n*24;
    for (int i = 0; i < 9; i++) o[i] = IR[i];
    o[9]  = aug[n*16 + 3];
    o[10] = aug[n*16 + 7];
    o[11] = aug[n*16 + 11];
    for (int i = 0; i < 3; i++)
        for (int j = 0; j < 3; j++) o[12 + i*3 + j] = IA[i*4 + j];
    o[21] = IA[3]; o[22] = IA[7]; o[23] = IA[11];
}

// ---------------- 2. transpose depthnet weights -> wT[c][96] ----------------
__global__ void lss_wt_kernel(const float* __restrict__ w_dep, float* __restrict__ wT) {
    int idx = blockIdx.x * 256 + threadIdx.x;   // 96*256 = 24576
    int o = idx / CIN, c = idx % CIN;
    wT[c * NOUT + o] = w_dep[idx];
}

// ---------------- 3. geometry: cell id per point (f32, np op order, no fma) --------
__global__ void lss_geom_kernel(const float* __restrict__ mats,
                                int* __restrict__ cellid,
                                int* __restrict__ counts) {
    int gp = blockIdx.x * 256 + threadIdx.x;    // [0, BN*HW)
    int bn = gp / HW, p = gp % HW;
    const float* m = mats + bn * 24;
    int ph = p / WF, pw = p % WF;
    float u = ((float)pw + 0.5f) * 8.0f;        // exact
    float v = ((float)ph + 0.5f) * 8.0f;        // exact
    // uv_raw = invR @ (uv1 - t_aug), sequential j, no fma
    float q0 = __fsub_rn(u, m[9]);
    float q1 = __fsub_rn(v, m[10]);
    float q2 = __fsub_rn(1.0f, m[11]);
    float r0 = __fadd_rn(__fadd_rn(__fmul_rn(m[0], q0), __fmul_rn(m[1], q1)), __fmul_rn(m[2], q2));
    float r1 = __fadd_rn(__fadd_rn(__fmul_rn(m[3], q0), __fmul_rn(m[4], q1)), __fmul_rn(m[5], q2));
    float r2 = __fadd_rn(__fadd_rn(__fmul_rn(m[6], q0), __fmul_rn(m[7], q1)), __fmul_rn(m[8], q2));
    int b = bn / NCAM;
    for (int d = 0; d < DBIN; d++) {
        float dv = __fmul_rn((float)d + 0.5f, 2.8125f);   // exact
        float p0 = __fmul_rn(r0, dv);
        float p1 = __fmul_rn(r1, dv);
        float p2 = __fmul_rn(r2, dv);
        float px = __fadd_rn(__fadd_rn(__fadd_rn(__fmul_rn(m[12], p0), __fmul_rn(m[13], p1)), __fmul_rn(m[14], p2)), m[21]);
        float py = __fadd_rn(__fadd_rn(__fadd_rn(__fmul_rn(m[15], p0), __fmul_rn(m[16], p1)), __fmul_rn(m[17], p2)), m[22]);
        float pz = __fadd_rn(__fadd_rn(__fadd_rn(__fmul_rn(m[18], p0), __fmul_rn(m[19], p1)), __fmul_rn(m[20], p2)), m[23]);
        float fx = floorf(__fdiv_rn(__fsub_rn(px, -51.2f), 0.8f));
        float fy = floorf(__fdiv_rn(__fsub_rn(py, -51.2f), 0.8f));
        int cell = -1;
        if (fx >= 0.0f && fx < 128.0f && fy >= 0.0f && fy < 128.0f && pz >= -5.0f && pz < 3.0f) {
            cell = b * (BEVH * BEVW) + (int)fy * BEVW + (int)fx;
            atomicAdd(&counts[cell], 1);
        }
        cellid[(bn * DBIN + d) * HW + p] = cell;
    }
}

// ---------------- 4. exclusive scan of counts -> starts, cursors (single block) ----
__global__ void lss_scan_kernel(const int* __restrict__ counts,
                                int* __restrict__ starts,
                                int* __restrict__ cursors) {
    __shared__ int sums[1024];
    int tid = threadIdx.x;
    int base = tid * 32;                 // 32768 / 1024
    int local[32];
    int s = 0;
    #pragma unroll
    for (int i = 0; i < 32; i++) { local[i] = s; s += counts[base + i]; }
    sums[tid] = s;
    __syncthreads();
    for (int off = 1; off < 1024; off <<= 1) {
        int v = 0;
        if (tid >= off) v = sums[tid - off];
        __syncthreads();
        if (tid >= off) sums[tid] += v;
        __syncthreads();
    }
    int offset = (tid > 0) ? sums[tid - 1] : 0;
    #pragma unroll
    for (int i = 0; i < 32; i++) {
        int st = offset + local[i];
        starts[base + i]  = st;
        cursors[base + i] = st;
    }
}

// ---------------- 5. fill CSR point list ----------------
__global__ void lss_fill_kernel(const int* __restrict__ cellid,
                                int* __restrict__ cursors,
                                int* __restrict__ plist) {
    int i = blockIdx.x * 256 + threadIdx.x;    // NPTS = 2112*256
    int c = cellid[i];
    if (c >= 0) {
        int pos = atomicAdd(&cursors[c], 1);
        plist[pos] = i;
    }
}

// ---------------- 6. depthnet GEMM + softmax -> yT[(bn,p), 96] ----------------
__global__ __launch_bounds__(256) void lss_gemm_kernel(const float* __restrict__ x,
                                                       const float* __restrict__ wT,
                                                       const float* __restrict__ b_dep,
                                                       float* __restrict__ yT) {
    int gp = blockIdx.x * 256 + threadIdx.x;   // pixel (bn,p); 33792 = 132*256
    int ob = blockIdx.y * 48;                  // o-half: [0,48) or [48,96)
    int bn = gp / HW, p = gp % HW;
    const float* xp = x + (size_t)bn * CIN * HW + p;
    float acc[48];
    #pragma unroll
    for (int o = 0; o < 48; o++) acc[o] = 0.f;
    for (int c = 0; c < CIN; c++) {
        float xv = xp[(size_t)c * HW];
        const float* wc = wT + c * NOUT + ob;   // uniform -> s_load
        #pragma unroll
        for (int o = 0; o < 48; o++) acc[o] = fmaf(wc[o], xv, acc[o]);
    }
    #pragma unroll
    for (int o = 0; o < 48; o++) acc[o] += b_dep[ob + o];
    float* yp = yT + (size_t)gp * NOUT;
    if (ob == 0) {
        float m = acc[0];
        #pragma unroll
        for (int o = 1; o < 16; o++) m = fmaxf(m, acc[o]);
        float e[16], s = 0.f;
        #pragma unroll
        for (int o = 0; o < 16; o++) { e[o] = expf(acc[o] - m); s += e[o]; }
        float inv = 1.f / s;
        #pragma unroll
        for (int o = 0; o < 16; o++) yp[o] = e[o] * inv;
        #pragma unroll
        for (int o = 16; o < 48; o++) yp[o] = acc[o];
    } else {
        #pragma unroll
        for (int o = 0; o < 48; o++) yp[48 + o] = acc[o];
    }
}

// ---------------- 7. per-cell gather + mean -> bev (NCHW) ----------------
__global__ __launch_bounds__(256) void lss_gather_kernel(const float* __restrict__ yT,
                                                         const int* __restrict__ starts,
                                                         const int* __restrict__ counts,
                                                         const int* __restrict__ plist,
                                                         float* __restrict__ bev) {
    __shared__ float red[4][80];
    int cell = blockIdx.x;
    int lane = threadIdx.x & 63;
    int wv   = threadIdx.x >> 6;
    int cnt  = counts[cell];
    int s    = starts[cell];
    float a0 = 0.f, a1 = 0.f;
    for (int j = wv; j < cnt; j += 4) {
        int pidx = plist[s + j];
        int bn  = pidx / (DBIN * HW);
        int rem = pidx % (DBIN * HW);
        int d   = rem / HW;
        int p   = rem % HW;
        const float* yp = yT + (size_t)(bn * HW + p) * NOUT;
        float dep = yp[d];
        a0 = fmaf(dep, yp[16 + lane], a0);
        if (lane < 16) a1 = fmaf(dep, yp[80 + lane], a1);
    }
    red[wv][lane] = a0;
    if (lane < 16) red[wv][64 + lane] = a1;
    __syncthreads();
    if (wv == 0) {
        float invc = 1.f / fmaxf((float)cnt, 1.f);
        int b  = cell >> 14;          // / 16384
        int yx = cell & 16383;
        float r0 = (red[0][lane] + red[1][lane]) + (red[2][lane] + red[3][lane]);
        bev[((size_t)(b * COUT + lane)) * (BEVH * BEVW) + yx] = r0 * invc;
        if (lane < 16) {
            float r1 = (red[0][64 + lane] + red[1][64 + lane]) + (red[2][64 + lane] + red[3][64 + lane]);
            bev[((size_t)(b * COUT + 64 + lane)) * (BEVH * BEVW) + yx] = r1 * invc;
        }
    }
}

// ---------------- 8. 3x3 SAME conv, NCHW, f32 ----------------
__global__ __launch_bounds__(128) void lss_conv_kernel(const float* __restrict__ bev,
                                                       const float* __restrict__ w,
                                                       const float* __restrict__ bias,
                                                       float* __restrict__ out) {
    constexpr int CICH = 20;
    __shared__ float lds[CICH][3][132];
    int row = blockIdx.x;              // 0..255 = b*128 + y
    int og  = blockIdx.y * 20;         // output-channel group
    int b = row >> 7, y = row & 127;
    int x = threadIdx.x;
    float acc[20];
    #pragma unroll
    for (int o = 0; o < 20; o++) acc[o] = 0.f;
    for (int cc = 0; cc < COUT; cc += CICH) {
        for (int idx = threadIdx.x; idx < CICH * 3 * 130; idx += 128) {
            int ci  = idx / 390;
            int rem = idx % 390;
            int dy  = rem / 130;
            int col = rem % 130;
            int xx  = col - 1;
            int yy  = y + dy - 1;
            float vv = 0.f;
            if (xx >= 0 && xx < 128 && yy >= 0 && yy < 128)
                vv = bev[((size_t)(b * COUT + cc + ci) * BEVH + yy) * BEVW + xx];
            lds[ci][dy][col] = vv;
        }
        __syncthreads();
        for (int ci = 0; ci < CICH; ci++) {
            float v00 = lds[ci][0][x], v01 = lds[ci][0][x + 1], v02 = lds[ci][0][x + 2];
            float v10 = lds[ci][1][x], v11 = lds[ci][1][x + 1], v12 = lds[ci][1][x + 2];
            float v20 = lds[ci][2][x], v21 = lds[ci][2][x + 1], v22 = lds[ci][2][x + 2];
            #pragma unroll
            for (int o = 0; o < 20; o++) {
                const float* wp = w + ((size_t)(og + o) * COUT + cc + ci) * 9;  // uniform -> s_load
                acc[o] = fmaf(wp[0], v00, acc[o]);
                acc[o] = fmaf(wp[1], v01, acc[o]);
                acc[o] = fmaf(wp[2], v02, acc[o]);
                acc[o] = fmaf(wp[3], v10, acc[o]);
                acc[o] = fmaf(wp[4], v11, acc[o]);
                acc[o] = fmaf(wp[5], v12, acc[o]);
                acc[o] = fmaf(wp[6], v20, acc[o]);
                acc[o] = fmaf(wp[7], v21, acc[o]);
                acc[o] = fmaf(wp[8], v22, acc[o]);
            }
        }
        __syncthreads();
    }
    #pragma unroll
    for (int o = 0; o < 20; o++)
        out[((size_t)(b * COUT + og + o) * BEVH + y) * BEVW + x] = acc[o] + bias[og + o];
}

// ---------------- launch ----------------
extern "C" void kernel_launch(void* const* d_in, const int* in_sizes, int n_in,
                              void* d_out, int out_size, void* d_ws, size_t ws_size,
                              hipStream_t stream) {
    (void)in_sizes; (void)n_in; (void)out_size; (void)ws_size;
    const float* x     = (const float*)d_in[0];
    const float* l2i   = (const float*)d_in[1];
    const float* aug   = (const float*)d_in[2];
    const float* w_dep = (const float*)d_in[3];
    const float* b_dep = (const float*)d_in[4];
    const float* w_ref = (const float*)d_in[5];
    const float* b_ref = (const float*)d_in[6];
    float* out = (float*)d_out;

    char* ws = (char*)d_ws;
    float*  mats  = (float*)(ws + MATS_OFF);
    float*  wT    = (float*)(ws + WT_OFF);
    float*  yT    = (float*)(ws + YT_OFF);
    int*    cellid  = (int*)(ws + CELL_OFF);
    int*    counts  = (int*)(ws + COUNTS_OFF);
    int*    starts  = (int*)(ws + STARTS_OFF);
    int*    cursors = (int*)(ws + CURS_OFF);
    int*    plist   = (int*)(ws + PLIST_OFF);
    float*  bev     = (float*)(ws + BEV_OFF);

    hipMemsetAsync(counts, 0, NUMC * sizeof(int), stream);
    lss_prep_kernel<<<1, 64, 0, stream>>>(l2i, aug, mats);
    lss_wt_kernel<<<96, 256, 0, stream>>>(w_dep, wT);
    lss_geom_kernel<<<BN * HW / 256, 256, 0, stream>>>(mats, cellid, counts);
    lss_scan_kernel<<<1, 1024, 0, stream>>>(counts, starts, cursors);
    lss_fill_kernel<<<NPTS / 256, 256, 0, stream>>>(cellid, cursors, plist);
    lss_gemm_kernel<<<dim3(BN * HW / 256, 2), 256, 0, stream>>>(x, wT, b_dep, yT);
    lss_gather_kernel<<<NUMC, 256, 0, stream>>>(yT, starts, counts, plist, bev);
    lss_conv_kernel<<<dim3(B_ * BEVH, 4), 128, 0, stream>>>(bev, w_ref, b_ref, out);
}

// Round 3
// 483.216 us; speedup vs baseline: 1.4920x; 1.4920x over previous
//
#include <hip/hip_runtime.h>
#include <math.h>

// ---------------- problem constants ----------------
namespace {
constexpr int B_   = 2;
constexpr int NCAM = 6;
constexpr int BN   = 12;
constexpr int CIN  = 256;
constexpr int COUT = 80;
constexpr int DBIN = 16;
constexpr int NOUT = 96;            // DBIN + COUT
constexpr int HF = 32, WF = 88;
constexpr int HW = HF * WF;         // 2816
constexpr int BEVH = 128, BEVW = 128;
constexpr int NUMC = B_ * BEVH * BEVW;   // 32768
constexpr int NPTS = BN * DBIN * HW;     // 540672

// ws layout (byte offsets)
constexpr size_t MATS_OFF   = 0;                            // 12*24 f32
constexpr size_t WT_OFF     = 2048;                         // 24576 f32 = 98304
constexpr size_t YT_OFF     = 102400;                       // 12*2816*96 f32 = 12976128
                                                            // (reused as bevCHW after gather)
constexpr size_t CELL_OFF   = YT_OFF + 12976128;            // NPTS i32 = 2162688
constexpr size_t COUNTS_OFF = CELL_OFF + 2162688;           // NUMC i32 = 131072
constexpr size_t STARTS_OFF = COUNTS_OFF + 131072;          // (NUMC+1) i32, padded
constexpr size_t CURS_OFF   = STARTS_OFF + 131584;          // NUMC i32
constexpr size_t PLIST_OFF  = CURS_OFF + 131072;            // NPTS i32 (fused (row<<4)|d)
constexpr size_t PCELL_OFF  = PLIST_OFF + 2162688;          // NPTS i32 (cell per sorted pos)
constexpr size_t BEVHWC_OFF = PCELL_OFF + 2162688;          // NUMC*80 f32 = 10485760
}

// ---------------- f32 LU inverse, LAPACK gesv-style ----------------
template<int NM>
__device__ void inv_lu_f32(float* A, float* Y) {
    int piv[NM];
    for (int j = 0; j < NM; j++) {
        int p = j; float mx = fabsf(A[j*NM+j]);
        for (int i = j+1; i < NM; i++) { float v = fabsf(A[i*NM+j]); if (v > mx) { mx = v; p = i; } }
        piv[j] = p;
        if (p != j) for (int k = 0; k < NM; k++) { float t = A[j*NM+k]; A[j*NM+k] = A[p*NM+k]; A[p*NM+k] = t; }
        float r = __fdiv_rn(1.0f, A[j*NM+j]);
        for (int i = j+1; i < NM; i++) A[i*NM+j] = __fmul_rn(A[i*NM+j], r);
        for (int i = j+1; i < NM; i++) {
            float lij = A[i*NM+j];
            for (int k = j+1; k < NM; k++)
                A[i*NM+k] = __fsub_rn(A[i*NM+k], __fmul_rn(lij, A[j*NM+k]));
        }
    }
    for (int c = 0; c < NM; c++) {
        float x[NM];
        for (int i = 0; i < NM; i++) x[i] = 0.f;
        x[c] = 1.f;
        for (int j = 0; j < NM; j++) { int p = piv[j]; if (p != j) { float t = x[j]; x[j] = x[p]; x[p] = t; } }
        for (int k = 0; k < NM; k++) {
            float xk = x[k];
            for (int i = k+1; i < NM; i++) x[i] = __fsub_rn(x[i], __fmul_rn(xk, A[i*NM+k]));
        }
        for (int k = NM-1; k >= 0; k--) {
            float xk = __fdiv_rn(x[k], A[k*NM+k]);
            x[k] = xk;
            for (int i = 0; i < k; i++) x[i] = __fsub_rn(x[i], __fmul_rn(xk, A[i*NM+k]));
        }
        for (int i = 0; i < NM; i++) Y[i*NM+c] = x[i];
    }
}

// ---------------- 1. per-camera transforms (f32, reference semantics) -------------
__global__ void lss_prep_kernel(const float* __restrict__ l2i,
                                const float* __restrict__ aug,
                                float* __restrict__ mats) {
    int n = threadIdx.x;
    if (n >= BN) return;
    float A[16], IA[16];
    for (int i = 0; i < 16; i++) A[i] = l2i[n*16 + i];
    inv_lu_f32<4>(A, IA);
    float R[9], IR[9];
    for (int i = 0; i < 3; i++)
        for (int j = 0; j < 3; j++) R[i*3+j] = aug[n*16 + i*4 + j];
    inv_lu_f32<3>(R, IR);
    float* o = mats + n*24;
    for (int i = 0; i < 9; i++) o[i] = IR[i];
    o[9]  = aug[n*16 + 3];
    o[10] = aug[n*16 + 7];
    o[11] = aug[n*16 + 11];
    for (int i = 0; i < 3; i++)
        for (int j = 0; j < 3; j++) o[12 + i*3 + j] = IA[i*4 + j];
    o[21] = IA[3]; o[22] = IA[7]; o[23] = IA[11];
}

// ---------------- 2. transpose depthnet weights -> wT[c][96] ----------------
__global__ void lss_wt_kernel(const float* __restrict__ w_dep, float* __restrict__ wT) {
    int idx = blockIdx.x * 256 + threadIdx.x;   // 96*256 = 24576
    int o = idx / CIN, c = idx % CIN;
    wT[c * NOUT + o] = w_dep[idx];
}

// ---------------- 3. geometry: cell per point (f32, np semantics) ----------------
// counts via wave-run-aggregated atomics (lanes = consecutive pixels -> long runs)
__global__ void lss_geom_kernel(const float* __restrict__ mats,
                                int* __restrict__ cellid,
                                int* __restrict__ counts) {
    int gp = blockIdx.x * 256 + threadIdx.x;    // [0, BN*HW)
    int lane = threadIdx.x & 63;
    int bn = gp / HW, p = gp % HW;
    const float* m = mats + bn * 24;
    int ph = p / WF, pw = p % WF;
    float u = ((float)pw + 0.5f) * 8.0f;
    float v = ((float)ph + 0.5f) * 8.0f;
    float q0 = __fsub_rn(u, m[9]);
    float q1 = __fsub_rn(v, m[10]);
    float q2 = __fsub_rn(1.0f, m[11]);
    float r0 = __fadd_rn(__fadd_rn(__fmul_rn(m[0], q0), __fmul_rn(m[1], q1)), __fmul_rn(m[2], q2));
    float r1 = __fadd_rn(__fadd_rn(__fmul_rn(m[3], q0), __fmul_rn(m[4], q1)), __fmul_rn(m[5], q2));
    float r2 = __fadd_rn(__fadd_rn(__fmul_rn(m[6], q0), __fmul_rn(m[7], q1)), __fmul_rn(m[8], q2));
    int b = bn / NCAM;
    for (int d = 0; d < DBIN; d++) {
        float dv = __fmul_rn((float)d + 0.5f, 2.8125f);
        float p0 = __fmul_rn(r0, dv);
        float p1 = __fmul_rn(r1, dv);
        float p2 = __fmul_rn(r2, dv);
        float px = __fadd_rn(__fadd_rn(__fadd_rn(__fmul_rn(m[12], p0), __fmul_rn(m[13], p1)), __fmul_rn(m[14], p2)), m[21]);
        float py = __fadd_rn(__fadd_rn(__fadd_rn(__fmul_rn(m[15], p0), __fmul_rn(m[16], p1)), __fmul_rn(m[17], p2)), m[22]);
        float pz = __fadd_rn(__fadd_rn(__fadd_rn(__fmul_rn(m[18], p0), __fmul_rn(m[19], p1)), __fmul_rn(m[20], p2)), m[23]);
        float fx = floorf(__fdiv_rn(__fsub_rn(px, -51.2f), 0.8f));
        float fy = floorf(__fdiv_rn(__fsub_rn(py, -51.2f), 0.8f));
        int cell = -1;
        if (fx >= 0.0f && fx < 128.0f && fy >= 0.0f && fy < 128.0f && pz >= -5.0f && pz < 3.0f)
            cell = b * (BEVH * BEVW) + (int)fy * BEVW + (int)fx;
        cellid[(bn * DBIN + d) * HW + p] = cell;
        // wave-run aggregation: one atomic per same-cell run
        int cprev = __shfl_up(cell, 1);
        bool leader = (lane == 0) || (cell != cprev);
        unsigned long long L = __ballot(leader);
        unsigned long long above = (lane == 63) ? 0ull : (L >> (lane + 1));
        int runlen = above ? __ffsll(above) : (64 - lane);
        if (leader && cell >= 0) atomicAdd(&counts[cell], runlen);
    }
}

// ---------------- 4. scan counts -> starts, cursors, total (single block) ---------
__global__ void lss_scan_kernel(const int* __restrict__ counts,
                                int* __restrict__ starts,
                                int* __restrict__ cursors) {
    __shared__ int sums[1024];
    int tid = threadIdx.x;
    int base = tid * 32;                 // 32768 / 1024
    int local[32];
    int s = 0;
    #pragma unroll
    for (int i = 0; i < 32; i++) { local[i] = s; s += counts[base + i]; }
    sums[tid] = s;
    __syncthreads();
    for (int off = 1; off < 1024; off <<= 1) {
        int v = 0;
        if (tid >= off) v = sums[tid - off];
        __syncthreads();
        if (tid >= off) sums[tid] += v;
        __syncthreads();
    }
    int offset = (tid > 0) ? sums[tid - 1] : 0;
    #pragma unroll
    for (int i = 0; i < 32; i++) {
        int st = offset + local[i];
        starts[base + i]  = st;
        cursors[base + i] = st;
    }
    if (tid == 1023) starts[NUMC] = sums[1023];   // total valid
}

// ---------------- 5. fill CSR (run-aggregated atomics, fused index) ---------------
__global__ void lss_fill_kernel(const int* __restrict__ cellid,
                                int* __restrict__ cursors,
                                int* __restrict__ plist,
                                int* __restrict__ pcell) {
    int i = blockIdx.x * 256 + threadIdx.x;    // NPTS = 2112*256
    int lane = threadIdx.x & 63;
    int c = cellid[i];
    // decode natural index -> fused yT index (row<<4)|d
    int bn  = i / (DBIN * HW);
    int rem = i % (DBIN * HW);
    int d   = rem / HW;
    int p   = rem % HW;
    int pf  = ((bn * HW + p) << 4) | d;
    // wave-run aggregation
    int cprev = __shfl_up(c, 1);
    bool leader = (lane == 0) || (c != cprev);
    unsigned long long L = __ballot(leader);
    unsigned long long above = (lane == 63) ? 0ull : (L >> (lane + 1));
    int runlen = above ? __ffsll(above) : (64 - lane);
    unsigned long long below = L & (~0ull >> (63 - lane));
    int lead = 63 - __clzll(below);
    int rank = lane - lead;
    int bse = 0;
    if (leader && c >= 0) bse = atomicAdd(&cursors[c], runlen);
    bse = __shfl(bse, lead);
    if (c >= 0) {
        plist[bse + rank] = pf;
        pcell[bse + rank] = c;
    }
}

// ---------------- 6. depthnet GEMM + softmax -> yT[(bn,p), 96] ----------------
__global__ __launch_bounds__(256) void lss_gemm_kernel(const float* __restrict__ x,
                                                       const float* __restrict__ wT,
                                                       const float* __restrict__ b_dep,
                                                       float* __restrict__ yT) {
    int gp = blockIdx.x * 256 + threadIdx.x;   // pixel (bn,p); 33792 = 132*256
    int ob = blockIdx.y * 48;                  // o-half
    int bn = gp / HW, p = gp % HW;
    const float* xp = x + (size_t)bn * CIN * HW + p;
    float acc[48];
    #pragma unroll
    for (int o = 0; o < 48; o++) acc[o] = 0.f;
    for (int c = 0; c < CIN; c++) {
        float xv = xp[(size_t)c * HW];
        const float* wc = wT + c * NOUT + ob;
        #pragma unroll
        for (int o = 0; o < 48; o++) acc[o] = fmaf(wc[o], xv, acc[o]);
    }
    #pragma unroll
    for (int o = 0; o < 48; o++) acc[o] += b_dep[ob + o];
    float* yp = yT + (size_t)gp * NOUT;
    if (ob == 0) {
        float m = acc[0];
        #pragma unroll
        for (int o = 1; o < 16; o++) m = fmaxf(m, acc[o]);
        float e[16], s = 0.f;
        #pragma unroll
        for (int o = 0; o < 16; o++) { e[o] = expf(acc[o] - m); s += e[o]; }
        float inv = 1.f / s;
        #pragma unroll
        for (int o = 0; o < 16; o++) yp[o] = e[o] * inv;
        #pragma unroll
        for (int o = 16; o < 48; o++) yp[o] = acc[o];
    } else {
        #pragma unroll
        for (int o = 0; o < 48; o++) yp[48 + o] = acc[o];
    }
}

// ---------------- 7. chunked segmented gather -> bevHWC (atomic flush) ------------
__global__ __launch_bounds__(256) void lss_gather_kernel(const float* __restrict__ yT,
                                                         const int* __restrict__ plist,
                                                         const int* __restrict__ pcell,
                                                         const int* __restrict__ nvptr,
                                                         float* __restrict__ bevHWC) {
    int wv   = threadIdx.x >> 6;
    int lane = threadIdx.x & 63;
    int pos0 = (blockIdx.x * 4 + wv) * 64;
    int nv = *nvptr;
    if (pos0 >= nv) return;
    int n = min(64, nv - pos0);
    const int* pl = plist + pos0;
    const int* pc = pcell + pos0;
    float a0 = 0.f, a1 = 0.f;
    int cur = pc[0];
    for (int j = 0; j < n; j++) {
        int c = pc[j];                     // wave-uniform
        if (c != cur) {
            atomicAdd(&bevHWC[(size_t)cur * COUT + lane], a0);
            if (lane < 16) atomicAdd(&bevHWC[(size_t)cur * COUT + 64 + lane], a1);
            a0 = a1 = 0.f;
            cur = c;
        }
        int pf = pl[j];
        const float* yp = yT + (size_t)(pf >> 4) * NOUT;
        float dep = yp[pf & 15];
        a0 = fmaf(dep, yp[16 + lane], a0);
        if (lane < 16) a1 = fmaf(dep, yp[80 + lane], a1);
    }
    atomicAdd(&bevHWC[(size_t)cur * COUT + lane], a0);
    if (lane < 16) atomicAdd(&bevHWC[(size_t)cur * COUT + 64 + lane], a1);
}

// ---------------- 8. transpose HWC->CHW + normalize by count ----------------------
__global__ __launch_bounds__(256) void lss_tr_kernel(const float* __restrict__ bevHWC,
                                                     const int* __restrict__ counts,
                                                     float* __restrict__ bevCHW) {
    __shared__ float t[COUT][65];
    __shared__ float ic[64];
    int tid = threadIdx.x;
    int cellbase = blockIdx.x * 64;
    if (tid < 64) {
        int cnt = counts[cellbase + tid];
        ic[tid] = 1.f / fmaxf((float)cnt, 1.f);
    }
    const float* src = bevHWC + (size_t)cellbase * COUT;
    #pragma unroll
    for (int k = 0; k < 20; k++) {
        int idx = tid + k * 256;           // 5120 = 20*256
        int yx = idx / COUT, ch = idx % COUT;
        t[ch][yx] = src[idx];
    }
    __syncthreads();
    int b  = cellbase >> 14;
    int yx0 = cellbase & 16383;
    #pragma unroll
    for (int k = 0; k < 20; k++) {
        int idx = tid + k * 256;
        int ch = idx / 64, yxl = idx % 64;
        bevCHW[((size_t)(b * COUT + ch)) * (BEVH * BEVW) + yx0 + yxl] = t[ch][yxl] * ic[yxl];
    }
}

// ---------------- 9. 3x3 SAME conv, NCHW, f32 ----------------
__global__ __launch_bounds__(128) void lss_conv_kernel(const float* __restrict__ bev,
                                                       const float* __restrict__ w,
                                                       const float* __restrict__ bias,
                                                       float* __restrict__ out) {
    constexpr int CICH = 20;
    __shared__ float lds[CICH][3][132];
    int row = blockIdx.x;              // 0..255 = b*128 + y
    int og  = blockIdx.y * 20;
    int b = row >> 7, y = row & 127;
    int x = threadIdx.x;
    float acc[20];
    #pragma unroll
    for (int o = 0; o < 20; o++) acc[o] = 0.f;
    for (int cc = 0; cc < COUT; cc += CICH) {
        for (int idx = threadIdx.x; idx < CICH * 3 * 130; idx += 128) {
            int ci  = idx / 390;
            int rem = idx % 390;
            int dy  = rem / 130;
            int col = rem % 130;
            int xx  = col - 1;
            int yy  = y + dy - 1;
            float vv = 0.f;
            if (xx >= 0 && xx < 128 && yy >= 0 && yy < 128)
                vv = bev[((size_t)(b * COUT + cc + ci) * BEVH + yy) * BEVW + xx];
            lds[ci][dy][col] = vv;
        }
        __syncthreads();
        for (int ci = 0; ci < CICH; ci++) {
            float v00 = lds[ci][0][x], v01 = lds[ci][0][x + 1], v02 = lds[ci][0][x + 2];
            float v10 = lds[ci][1][x], v11 = lds[ci][1][x + 1], v12 = lds[ci][1][x + 2];
            float v20 = lds[ci][2][x], v21 = lds[ci][2][x + 1], v22 = lds[ci][2][x + 2];
            #pragma unroll
            for (int o = 0; o < 20; o++) {
                const float* wp = w + ((size_t)(og + o) * COUT + cc + ci) * 9;
                acc[o] = fmaf(wp[0], v00, acc[o]);
                acc[o] = fmaf(wp[1], v01, acc[o]);
                acc[o] = fmaf(wp[2], v02, acc[o]);
                acc[o] = fmaf(wp[3], v10, acc[o]);
                acc[o] = fmaf(wp[4], v11, acc[o]);
                acc[o] = fmaf(wp[5], v12, acc[o]);
                acc[o] = fmaf(wp[6], v20, acc[o]);
                acc[o] = fmaf(wp[7], v21, acc[o]);
                acc[o] = fmaf(wp[8], v22, acc[o]);
            }
        }
        __syncthreads();
    }
    #pragma unroll
    for (int o = 0; o < 20; o++)
        out[((size_t)(b * COUT + og + o) * BEVH + y) * BEVW + x] = acc[o] + bias[og + o];
}

// ---------------- launch ----------------
extern "C" void kernel_launch(void* const* d_in, const int* in_sizes, int n_in,
                              void* d_out, int out_size, void* d_ws, size_t ws_size,
                              hipStream_t stream) {
    (void)in_sizes; (void)n_in; (void)out_size; (void)ws_size;
    const float* x     = (const float*)d_in[0];
    const float* l2i   = (const float*)d_in[1];
    const float* aug   = (const float*)d_in[2];
    const float* w_dep = (const float*)d_in[3];
    const float* b_dep = (const float*)d_in[4];
    const float* w_ref = (const float*)d_in[5];
    const float* b_ref = (const float*)d_in[6];
    float* out = (float*)d_out;

    char* ws = (char*)d_ws;
    float* mats    = (float*)(ws + MATS_OFF);
    float* wT      = (float*)(ws + WT_OFF);
    float* yT      = (float*)(ws + YT_OFF);     // reused as bevCHW after gather
    float* bevCHW  = (float*)(ws + YT_OFF);
    int*   cellid  = (int*)(ws + CELL_OFF);
    int*   counts  = (int*)(ws + COUNTS_OFF);
    int*   starts  = (int*)(ws + STARTS_OFF);
    int*   cursors = (int*)(ws + CURS_OFF);
    int*   plist   = (int*)(ws + PLIST_OFF);
    int*   pcell   = (int*)(ws + PCELL_OFF);
    float* bevHWC  = (float*)(ws + BEVHWC_OFF);

    hipMemsetAsync(counts, 0, NUMC * sizeof(int), stream);
    hipMemsetAsync(bevHWC, 0, (size_t)NUMC * COUT * sizeof(float), stream);
    lss_prep_kernel<<<1, 64, 0, stream>>>(l2i, aug, mats);
    lss_wt_kernel<<<96, 256, 0, stream>>>(w_dep, wT);
    lss_geom_kernel<<<BN * HW / 256, 256, 0, stream>>>(mats, cellid, counts);
    lss_scan_kernel<<<1, 1024, 0, stream>>>(counts, starts, cursors);
    lss_fill_kernel<<<NPTS / 256, 256, 0, stream>>>(cellid, cursors, plist, pcell);
    lss_gemm_kernel<<<dim3(BN * HW / 256, 2), 256, 0, stream>>>(x, wT, b_dep, yT);
    lss_gather_kernel<<<NPTS / 256, 256, 0, stream>>>(yT, plist, pcell, starts + NUMC, bevHWC);
    lss_tr_kernel<<<NUMC / 64, 256, 0, stream>>>(bevHWC, counts, bevCHW);
    lss_conv_kernel<<<dim3(B_ * BEVH, 4), 128, 0, stream>>>(bevCHW, w_ref, b_ref, out);
}

// Round 4
// 455.197 us; speedup vs baseline: 1.5839x; 1.0616x over previous
//
#include <hip/hip_runtime.h>
#include <math.h>

// ---------------- problem constants ----------------
namespace {
constexpr int B_   = 2;
constexpr int NCAM = 6;
constexpr int BN   = 12;
constexpr int CIN  = 256;
constexpr int COUT = 80;
constexpr int DBIN = 16;
constexpr int NOUT = 96;            // DBIN + COUT
constexpr int HF = 32, WF = 88;
constexpr int HW = HF * WF;         // 2816
constexpr int BEVH = 128, BEVW = 128;
constexpr int NUMC = B_ * BEVH * BEVW;   // 32768
constexpr int NPTS = BN * DBIN * HW;     // 540672

// ws layout (byte offsets)
constexpr size_t MATS_OFF   = 0;                            // 12*24 f32
constexpr size_t WT_OFF     = 2048;                         // 24576 f32 = 98304
constexpr size_t YT_OFF     = 102400;                       // 12*2816*96 f32 = 12976128
                                                            // (reused as bevCHW after gather)
constexpr size_t CELL_OFF   = YT_OFF + 12976128;            // NPTS i32 = 2162688
constexpr size_t COUNTS_OFF = CELL_OFF + 2162688;           // NUMC i32 = 131072
constexpr size_t STARTS_OFF = COUNTS_OFF + 131072;          // (NUMC+1) i32, padded
constexpr size_t CURS_OFF   = STARTS_OFF + 131584;          // NUMC i32
constexpr size_t PLIST_OFF  = CURS_OFF + 131072;            // NPTS i32 (fused (row<<4)|d)
constexpr size_t PCELL_OFF  = PLIST_OFF + 2162688;          // NPTS i32 (cell per sorted pos)
constexpr size_t BEVHWC_OFF = PCELL_OFF + 2162688;          // NUMC*80 f32 = 10485760
}

// ---------------- f32 LU inverse, LAPACK gesv-style ----------------
template<int NM>
__device__ void inv_lu_f32(float* A, float* Y) {
    int piv[NM];
    for (int j = 0; j < NM; j++) {
        int p = j; float mx = fabsf(A[j*NM+j]);
        for (int i = j+1; i < NM; i++) { float v = fabsf(A[i*NM+j]); if (v > mx) { mx = v; p = i; } }
        piv[j] = p;
        if (p != j) for (int k = 0; k < NM; k++) { float t = A[j*NM+k]; A[j*NM+k] = A[p*NM+k]; A[p*NM+k] = t; }
        float r = __fdiv_rn(1.0f, A[j*NM+j]);
        for (int i = j+1; i < NM; i++) A[i*NM+j] = __fmul_rn(A[i*NM+j], r);
        for (int i = j+1; i < NM; i++) {
            float lij = A[i*NM+j];
            for (int k = j+1; k < NM; k++)
                A[i*NM+k] = __fsub_rn(A[i*NM+k], __fmul_rn(lij, A[j*NM+k]));
        }
    }
    for (int c = 0; c < NM; c++) {
        float x[NM];
        for (int i = 0; i < NM; i++) x[i] = 0.f;
        x[c] = 1.f;
        for (int j = 0; j < NM; j++) { int p = piv[j]; if (p != j) { float t = x[j]; x[j] = x[p]; x[p] = t; } }
        for (int k = 0; k < NM; k++) {
            float xk = x[k];
            for (int i = k+1; i < NM; i++) x[i] = __fsub_rn(x[i], __fmul_rn(xk, A[i*NM+k]));
        }
        for (int k = NM-1; k >= 0; k--) {
            float xk = __fdiv_rn(x[k], A[k*NM+k]);
            x[k] = xk;
            for (int i = 0; i < k; i++) x[i] = __fsub_rn(x[i], __fmul_rn(xk, A[i*NM+k]));
        }
        for (int i = 0; i < NM; i++) Y[i*NM+c] = x[i];
    }
}

// ---------------- 1. per-camera transforms (f32, reference semantics) -------------
__global__ void lss_prep_kernel(const float* __restrict__ l2i,
                                const float* __restrict__ aug,
                                float* __restrict__ mats) {
    int n = threadIdx.x;
    if (n >= BN) return;
    float A[16], IA[16];
    for (int i = 0; i < 16; i++) A[i] = l2i[n*16 + i];
    inv_lu_f32<4>(A, IA);
    float R[9], IR[9];
    for (int i = 0; i < 3; i++)
        for (int j = 0; j < 3; j++) R[i*3+j] = aug[n*16 + i*4 + j];
    inv_lu_f32<3>(R, IR);
    float* o = mats + n*24;
    for (int i = 0; i < 9; i++) o[i] = IR[i];
    o[9]  = aug[n*16 + 3];
    o[10] = aug[n*16 + 7];
    o[11] = aug[n*16 + 11];
    for (int i = 0; i < 3; i++)
        for (int j = 0; j < 3; j++) o[12 + i*3 + j] = IA[i*4 + j];
    o[21] = IA[3]; o[22] = IA[7]; o[23] = IA[11];
}

// ---------------- 2. transpose depthnet weights -> wT[c][96] ----------------
__global__ void lss_wt_kernel(const float* __restrict__ w_dep, float* __restrict__ wT) {
    int idx = blockIdx.x * 256 + threadIdx.x;   // 96*256 = 24576
    int o = idx / CIN, c = idx % CIN;
    wT[c * NOUT + o] = w_dep[idx];
}

// ---------------- 3. geometry: cell per point (f32, np semantics) ----------------
__global__ void lss_geom_kernel(const float* __restrict__ mats,
                                int* __restrict__ cellid,
                                int* __restrict__ counts) {
    int gp = blockIdx.x * 256 + threadIdx.x;    // [0, BN*HW)
    int lane = threadIdx.x & 63;
    int bn = gp / HW, p = gp % HW;
    const float* m = mats + bn * 24;
    int ph = p / WF, pw = p % WF;
    float u = ((float)pw + 0.5f) * 8.0f;
    float v = ((float)ph + 0.5f) * 8.0f;
    float q0 = __fsub_rn(u, m[9]);
    float q1 = __fsub_rn(v, m[10]);
    float q2 = __fsub_rn(1.0f, m[11]);
    float r0 = __fadd_rn(__fadd_rn(__fmul_rn(m[0], q0), __fmul_rn(m[1], q1)), __fmul_rn(m[2], q2));
    float r1 = __fadd_rn(__fadd_rn(__fmul_rn(m[3], q0), __fmul_rn(m[4], q1)), __fmul_rn(m[5], q2));
    float r2 = __fadd_rn(__fadd_rn(__fmul_rn(m[6], q0), __fmul_rn(m[7], q1)), __fmul_rn(m[8], q2));
    int b = bn / NCAM;
    for (int d = 0; d < DBIN; d++) {
        float dv = __fmul_rn((float)d + 0.5f, 2.8125f);
        float p0 = __fmul_rn(r0, dv);
        float p1 = __fmul_rn(r1, dv);
        float p2 = __fmul_rn(r2, dv);
        float px = __fadd_rn(__fadd_rn(__fadd_rn(__fmul_rn(m[12], p0), __fmul_rn(m[13], p1)), __fmul_rn(m[14], p2)), m[21]);
        float py = __fadd_rn(__fadd_rn(__fadd_rn(__fmul_rn(m[15], p0), __fmul_rn(m[16], p1)), __fmul_rn(m[17], p2)), m[22]);
        float pz = __fadd_rn(__fadd_rn(__fadd_rn(__fmul_rn(m[18], p0), __fmul_rn(m[19], p1)), __fmul_rn(m[20], p2)), m[23]);
        float fx = floorf(__fdiv_rn(__fsub_rn(px, -51.2f), 0.8f));
        float fy = floorf(__fdiv_rn(__fsub_rn(py, -51.2f), 0.8f));
        int cell = -1;
        if (fx >= 0.0f && fx < 128.0f && fy >= 0.0f && fy < 128.0f && pz >= -5.0f && pz < 3.0f)
            cell = b * (BEVH * BEVW) + (int)fy * BEVW + (int)fx;
        cellid[(bn * DBIN + d) * HW + p] = cell;
        int cprev = __shfl_up(cell, 1);
        bool leader = (lane == 0) || (cell != cprev);
        unsigned long long L = __ballot(leader);
        unsigned long long above = (lane == 63) ? 0ull : (L >> (lane + 1));
        int runlen = above ? __ffsll(above) : (64 - lane);
        if (leader && cell >= 0) atomicAdd(&counts[cell], runlen);
    }
}

// ---------------- 4. scan counts -> starts, cursors, total (single block) ---------
__global__ void lss_scan_kernel(const int* __restrict__ counts,
                                int* __restrict__ starts,
                                int* __restrict__ cursors) {
    __shared__ int sums[1024];
    int tid = threadIdx.x;
    int base = tid * 32;                 // 32768 / 1024
    int local[32];
    int s = 0;
    #pragma unroll
    for (int i = 0; i < 32; i++) { local[i] = s; s += counts[base + i]; }
    sums[tid] = s;
    __syncthreads();
    for (int off = 1; off < 1024; off <<= 1) {
        int v = 0;
        if (tid >= off) v = sums[tid - off];
        __syncthreads();
        if (tid >= off) sums[tid] += v;
        __syncthreads();
    }
    int offset = (tid > 0) ? sums[tid - 1] : 0;
    #pragma unroll
    for (int i = 0; i < 32; i++) {
        int st = offset + local[i];
        starts[base + i]  = st;
        cursors[base + i] = st;
    }
    if (tid == 1023) starts[NUMC] = sums[1023];   // total valid
}

// ---------------- 5. fill CSR (run-aggregated atomics, fused index) ---------------
__global__ void lss_fill_kernel(const int* __restrict__ cellid,
                                int* __restrict__ cursors,
                                int* __restrict__ plist,
                                int* __restrict__ pcell) {
    int i = blockIdx.x * 256 + threadIdx.x;    // NPTS = 2112*256
    int lane = threadIdx.x & 63;
    int c = cellid[i];
    int bn  = i / (DBIN * HW);
    int rem = i % (DBIN * HW);
    int d   = rem / HW;
    int p   = rem % HW;
    int pf  = ((bn * HW + p) << 4) | d;
    int cprev = __shfl_up(c, 1);
    bool leader = (lane == 0) || (c != cprev);
    unsigned long long L = __ballot(leader);
    unsigned long long above = (lane == 63) ? 0ull : (L >> (lane + 1));
    int runlen = above ? __ffsll(above) : (64 - lane);
    unsigned long long below = L & (~0ull >> (63 - lane));
    int lead = 63 - __clzll(below);
    int rank = lane - lead;
    int bse = 0;
    if (leader && c >= 0) bse = atomicAdd(&cursors[c], runlen);
    bse = __shfl(bse, lead);
    if (c >= 0) {
        plist[bse + rank] = pf;
        pcell[bse + rank] = c;
    }
}

// ---------------- 6. depthnet GEMM + softmax -> yT[(bn,p), 96] ----------------
__global__ __launch_bounds__(256) void lss_gemm_kernel(const float* __restrict__ x,
                                                       const float* __restrict__ wT,
                                                       const float* __restrict__ b_dep,
                                                       float* __restrict__ yT) {
    int gp = blockIdx.x * 256 + threadIdx.x;   // pixel (bn,p); 33792 = 132*256
    int ob = blockIdx.y * 48;                  // o-half
    int bn = gp / HW, p = gp % HW;
    const float* xp = x + (size_t)bn * CIN * HW + p;
    float acc[48];
    #pragma unroll
    for (int o = 0; o < 48; o++) acc[o] = 0.f;
    for (int c = 0; c < CIN; c++) {
        float xv = xp[(size_t)c * HW];
        const float* wc = wT + c * NOUT + ob;
        #pragma unroll
        for (int o = 0; o < 48; o++) acc[o] = fmaf(wc[o], xv, acc[o]);
    }
    #pragma unroll
    for (int o = 0; o < 48; o++) acc[o] += b_dep[ob + o];
    float* yp = yT + (size_t)gp * NOUT;
    if (ob == 0) {
        float m = acc[0];
        #pragma unroll
        for (int o = 1; o < 16; o++) m = fmaxf(m, acc[o]);
        float e[16], s = 0.f;
        #pragma unroll
        for (int o = 0; o < 16; o++) { e[o] = expf(acc[o] - m); s += e[o]; }
        float inv = 1.f / s;
        #pragma unroll
        for (int o = 0; o < 16; o++) yp[o] = e[o] * inv;
        #pragma unroll
        for (int o = 16; o < 48; o++) yp[o] = acc[o];
    } else {
        #pragma unroll
        for (int o = 0; o < 48; o++) yp[48 + o] = acc[o];
    }
}

// ---------------- 7. chunked segmented gather -> bevHWC (atomic flush) ------------
__global__ __launch_bounds__(256) void lss_gather_kernel(const float* __restrict__ yT,
                                                         const int* __restrict__ plist,
                                                         const int* __restrict__ pcell,
                                                         const int* __restrict__ nvptr,
                                                         float* __restrict__ bevHWC) {
    int wv   = threadIdx.x >> 6;
    int lane = threadIdx.x & 63;
    int pos0 = (blockIdx.x * 4 + wv) * 64;
    int nv = *nvptr;
    if (pos0 >= nv) return;
    int n = min(64, nv - pos0);
    const int* pl = plist + pos0;
    const int* pc = pcell + pos0;
    float a0 = 0.f, a1 = 0.f;
    int cur = pc[0];
    for (int j = 0; j < n; j++) {
        int c = pc[j];                     // wave-uniform
        if (c != cur) {
            atomicAdd(&bevHWC[(size_t)cur * COUT + lane], a0);
            if (lane < 16) atomicAdd(&bevHWC[(size_t)cur * COUT + 64 + lane], a1);
            a0 = a1 = 0.f;
            cur = c;
        }
        int pf = pl[j];
        const float* yp = yT + (size_t)(pf >> 4) * NOUT;
        float dep = yp[pf & 15];
        a0 = fmaf(dep, yp[16 + lane], a0);
        if (lane < 16) a1 = fmaf(dep, yp[80 + lane], a1);
    }
    atomicAdd(&bevHWC[(size_t)cur * COUT + lane], a0);
    if (lane < 16) atomicAdd(&bevHWC[(size_t)cur * COUT + 64 + lane], a1);
}

// ---------------- 8. transpose HWC->CHW + normalize by count ----------------------
__global__ __launch_bounds__(256) void lss_tr_kernel(const float* __restrict__ bevHWC,
                                                     const int* __restrict__ counts,
                                                     float* __restrict__ bevCHW) {
    __shared__ float t[COUT][65];
    __shared__ float ic[64];
    int tid = threadIdx.x;
    int cellbase = blockIdx.x * 64;
    if (tid < 64) {
        int cnt = counts[cellbase + tid];
        ic[tid] = 1.f / fmaxf((float)cnt, 1.f);
    }
    const float* src = bevHWC + (size_t)cellbase * COUT;
    #pragma unroll
    for (int k = 0; k < 20; k++) {
        int idx = tid + k * 256;           // 5120 = 20*256
        int yx = idx / COUT, ch = idx % COUT;
        t[ch][yx] = src[idx];
    }
    __syncthreads();
    int b  = cellbase >> 14;
    int yx0 = cellbase & 16383;
    #pragma unroll
    for (int k = 0; k < 20; k++) {
        int idx = tid + k * 256;
        int ch = idx / 64, yxl = idx % 64;
        bevCHW[((size_t)(b * COUT + ch)) * (BEVH * BEVW) + yx0 + yxl] = t[ch][yxl] * ic[yxl];
    }
}

// ---------------- 9. 3x3 SAME conv, NCHW, f32 ----------------
// block: 256 thr = 8 rows x 128 cols of output, og-group of 5 channels.
// thread: 4 consecutive rows x 1 col x 5 och (20 accs), 6x3 register window.
// ci staged in LDS chunks of 8 (10-row halo). Weight dword : wave-FMA = 1:16.
__global__ __launch_bounds__(256) void lss_conv_kernel(const float* __restrict__ bev,
                                                       const float* __restrict__ w,
                                                       const float* __restrict__ bias,
                                                       float* __restrict__ out) {
    constexpr int CICH = 8;
    __shared__ float lds[CICH][10][132];
    int rg = blockIdx.x;               // 0..31
    int b  = rg >> 4;
    int y0 = (rg & 15) * 8;
    int og = blockIdx.y * 5;
    int x  = threadIdx.x & 127;
    int ry = (threadIdx.x >> 7) * 4;   // 0 or 4: first of this thread's 4 rows
    float acc[5][4];
    #pragma unroll
    for (int o = 0; o < 5; o++)
        #pragma unroll
        for (int j = 0; j < 4; j++) acc[o][j] = 0.f;

    for (int cc = 0; cc < COUT; cc += CICH) {
        if (cc) __syncthreads();
        for (int idx = threadIdx.x; idx < CICH * 10 * 130; idx += 256) {
            int ci  = idx / 1300;
            int rem = idx % 1300;
            int dy  = rem / 130;
            int col = rem % 130;
            int yy = y0 + dy - 1;
            int xx = col - 1;
            float vv = 0.f;
            if (xx >= 0 && xx < 128 && yy >= 0 && yy < 128)
                vv = bev[((size_t)(b * COUT + cc + ci) * BEVH + yy) * BEVW + xx];
            lds[ci][dy][col] = vv;
        }
        __syncthreads();
        for (int ci = 0; ci < CICH; ci++) {
            float win[6][3];
            #pragma unroll
            for (int r = 0; r < 6; r++) {
                win[r][0] = lds[ci][ry + r][x];
                win[r][1] = lds[ci][ry + r][x + 1];
                win[r][2] = lds[ci][ry + r][x + 2];
            }
            #pragma unroll
            for (int o = 0; o < 5; o++) {
                const float* wp = w + ((size_t)(og + o) * COUT + cc + ci) * 9;  // uniform -> s_load
                #pragma unroll
                for (int j = 0; j < 4; j++) {
                    acc[o][j] = fmaf(wp[0], win[j][0],     acc[o][j]);
                    acc[o][j] = fmaf(wp[1], win[j][1],     acc[o][j]);
                    acc[o][j] = fmaf(wp[2], win[j][2],     acc[o][j]);
                    acc[o][j] = fmaf(wp[3], win[j + 1][0], acc[o][j]);
                    acc[o][j] = fmaf(wp[4], win[j + 1][1], acc[o][j]);
                    acc[o][j] = fmaf(wp[5], win[j + 1][2], acc[o][j]);
                    acc[o][j] = fmaf(wp[6], win[j + 2][0], acc[o][j]);
                    acc[o][j] = fmaf(wp[7], win[j + 2][1], acc[o][j]);
                    acc[o][j] = fmaf(wp[8], win[j + 2][2], acc[o][j]);
                }
            }
        }
    }
    #pragma unroll
    for (int o = 0; o < 5; o++) {
        float bi = bias[og + o];
        #pragma unroll
        for (int j = 0; j < 4; j++)
            out[((size_t)(b * COUT + og + o) * BEVH + (y0 + ry + j)) * BEVW + x] = acc[o][j] + bi;
    }
}

// ---------------- launch ----------------
extern "C" void kernel_launch(void* const* d_in, const int* in_sizes, int n_in,
                              void* d_out, int out_size, void* d_ws, size_t ws_size,
                              hipStream_t stream) {
    (void)in_sizes; (void)n_in; (void)out_size; (void)ws_size;
    const float* x     = (const float*)d_in[0];
    const float* l2i   = (const float*)d_in[1];
    const float* aug   = (const float*)d_in[2];
    const float* w_dep = (const float*)d_in[3];
    const float* b_dep = (const float*)d_in[4];
    const float* w_ref = (const float*)d_in[5];
    const float* b_ref = (const float*)d_in[6];
    float* out = (float*)d_out;

    char* ws = (char*)d_ws;
    float* mats    = (float*)(ws + MATS_OFF);
    float* wT      = (float*)(ws + WT_OFF);
    float* yT      = (float*)(ws + YT_OFF);     // reused as bevCHW after gather
    float* bevCHW  = (float*)(ws + YT_OFF);
    int*   cellid  = (int*)(ws + CELL_OFF);
    int*   counts  = (int*)(ws + COUNTS_OFF);
    int*   starts  = (int*)(ws + STARTS_OFF);
    int*   cursors = (int*)(ws + CURS_OFF);
    int*   plist   = (int*)(ws + PLIST_OFF);
    int*   pcell   = (int*)(ws + PCELL_OFF);
    float* bevHWC  = (float*)(ws + BEVHWC_OFF);

    hipMemsetAsync(counts, 0, NUMC * sizeof(int), stream);
    hipMemsetAsync(bevHWC, 0, (size_t)NUMC * COUT * sizeof(float), stream);
    lss_prep_kernel<<<1, 64, 0, stream>>>(l2i, aug, mats);
    lss_wt_kernel<<<96, 256, 0, stream>>>(w_dep, wT);
    lss_geom_kernel<<<BN * HW / 256, 256, 0, stream>>>(mats, cellid, counts);
    lss_scan_kernel<<<1, 1024, 0, stream>>>(counts, starts, cursors);
    lss_fill_kernel<<<NPTS / 256, 256, 0, stream>>>(cellid, cursors, plist, pcell);
    lss_gemm_kernel<<<dim3(BN * HW / 256, 2), 256, 0, stream>>>(x, wT, b_dep, yT);
    lss_gather_kernel<<<NPTS / 256, 256, 0, stream>>>(yT, plist, pcell, starts + NUMC, bevHWC);
    lss_tr_kernel<<<NUMC / 64, 256, 0, stream>>>(bevHWC, counts, bevCHW);
    lss_conv_kernel<<<dim3(32, 16), 256, 0, stream>>>(bevCHW, w_ref, b_ref, out);
}

// Round 5
// 397.662 us; speedup vs baseline: 1.8130x; 1.1447x over previous
//
#include <hip/hip_runtime.h>
#include <math.h>

// ---------------- problem constants ----------------
namespace {
constexpr int B_   = 2;
constexpr int NCAM = 6;
constexpr int BN   = 12;
constexpr int CIN  = 256;
constexpr int COUT = 80;
constexpr int DBIN = 16;
constexpr int NOUT = 96;            // DBIN + COUT
constexpr int HF = 32, WF = 88;
constexpr int HW = HF * WF;         // 2816
constexpr int BEVH = 128, BEVW = 128;
constexpr int NUMC = B_ * BEVH * BEVW;   // 32768
constexpr int NPTS = BN * DBIN * HW;     // 540672

// ws layout (byte offsets)
constexpr size_t MATS_OFF   = 0;                            // 12*24 f32
constexpr size_t WT_OFF     = 2048;                         // 24576 f32 = 98304
constexpr size_t YT_OFF     = 102400;                       // 12*2816*96 f32 = 12976128
                                                            // (reused as bevCHW after gather)
constexpr size_t CELL_OFF   = YT_OFF + 12976128;            // NPTS i32 = 2162688
constexpr size_t COUNTS_OFF = CELL_OFF + 2162688;           // NUMC i32 = 131072
constexpr size_t STARTS_OFF = COUNTS_OFF + 131072;          // (NUMC+1) i32, padded
constexpr size_t CURS_OFF   = STARTS_OFF + 131584;          // NUMC i32
constexpr size_t PLIST_OFF  = CURS_OFF + 131072;            // NPTS i32 (fused (row<<4)|d)
constexpr size_t PCELL_OFF  = PLIST_OFF + 2162688;          // NPTS i32 (cell per sorted pos)
constexpr size_t BEVHWC_OFF = PCELL_OFF + 2162688;          // NUMC*80 f32 = 10485760
}

// ---------------- f32 LU inverse, LAPACK gesv-style ----------------
template<int NM>
__device__ void inv_lu_f32(float* A, float* Y) {
    int piv[NM];
    for (int j = 0; j < NM; j++) {
        int p = j; float mx = fabsf(A[j*NM+j]);
        for (int i = j+1; i < NM; i++) { float v = fabsf(A[i*NM+j]); if (v > mx) { mx = v; p = i; } }
        piv[j] = p;
        if (p != j) for (int k = 0; k < NM; k++) { float t = A[j*NM+k]; A[j*NM+k] = A[p*NM+k]; A[p*NM+k] = t; }
        float r = __fdiv_rn(1.0f, A[j*NM+j]);
        for (int i = j+1; i < NM; i++) A[i*NM+j] = __fmul_rn(A[i*NM+j], r);
        for (int i = j+1; i < NM; i++) {
            float lij = A[i*NM+j];
            for (int k = j+1; k < NM; k++)
                A[i*NM+k] = __fsub_rn(A[i*NM+k], __fmul_rn(lij, A[j*NM+k]));
        }
    }
    for (int c = 0; c < NM; c++) {
        float x[NM];
        for (int i = 0; i < NM; i++) x[i] = 0.f;
        x[c] = 1.f;
        for (int j = 0; j < NM; j++) { int p = piv[j]; if (p != j) { float t = x[j]; x[j] = x[p]; x[p] = t; } }
        for (int k = 0; k < NM; k++) {
            float xk = x[k];
            for (int i = k+1; i < NM; i++) x[i] = __fsub_rn(x[i], __fmul_rn(xk, A[i*NM+k]));
        }
        for (int k = NM-1; k >= 0; k--) {
            float xk = __fdiv_rn(x[k], A[k*NM+k]);
            x[k] = xk;
            for (int i = 0; i < k; i++) x[i] = __fsub_rn(x[i], __fmul_rn(xk, A[i*NM+k]));
        }
        for (int i = 0; i < NM; i++) Y[i*NM+c] = x[i];
    }
}

// ---------------- 1. per-camera transforms (f32, reference semantics) -------------
__global__ void lss_prep_kernel(const float* __restrict__ l2i,
                                const float* __restrict__ aug,
                                float* __restrict__ mats) {
    int n = threadIdx.x;
    if (n >= BN) return;
    float A[16], IA[16];
    for (int i = 0; i < 16; i++) A[i] = l2i[n*16 + i];
    inv_lu_f32<4>(A, IA);
    float R[9], IR[9];
    for (int i = 0; i < 3; i++)
        for (int j = 0; j < 3; j++) R[i*3+j] = aug[n*16 + i*4 + j];
    inv_lu_f32<3>(R, IR);
    float* o = mats + n*24;
    for (int i = 0; i < 9; i++) o[i] = IR[i];
    o[9]  = aug[n*16 + 3];
    o[10] = aug[n*16 + 7];
    o[11] = aug[n*16 + 11];
    for (int i = 0; i < 3; i++)
        for (int j = 0; j < 3; j++) o[12 + i*3 + j] = IA[i*4 + j];
    o[21] = IA[3]; o[22] = IA[7]; o[23] = IA[11];
}

// ---------------- 2. transpose depthnet weights -> wT[c][96] ----------------
__global__ void lss_wt_kernel(const float* __restrict__ w_dep, float* __restrict__ wT) {
    int idx = blockIdx.x * 256 + threadIdx.x;   // 96*256 = 24576
    int o = idx / CIN, c = idx % CIN;
    wT[c * NOUT + o] = w_dep[idx];
}

// ---------------- 3. geometry: cell per point (f32, np semantics) ----------------
__global__ void lss_geom_kernel(const float* __restrict__ mats,
                                int* __restrict__ cellid,
                                int* __restrict__ counts) {
    int gp = blockIdx.x * 256 + threadIdx.x;    // [0, BN*HW)
    int lane = threadIdx.x & 63;
    int bn = gp / HW, p = gp % HW;
    const float* m = mats + bn * 24;
    int ph = p / WF, pw = p % WF;
    float u = ((float)pw + 0.5f) * 8.0f;
    float v = ((float)ph + 0.5f) * 8.0f;
    float q0 = __fsub_rn(u, m[9]);
    float q1 = __fsub_rn(v, m[10]);
    float q2 = __fsub_rn(1.0f, m[11]);
    float r0 = __fadd_rn(__fadd_rn(__fmul_rn(m[0], q0), __fmul_rn(m[1], q1)), __fmul_rn(m[2], q2));
    float r1 = __fadd_rn(__fadd_rn(__fmul_rn(m[3], q0), __fmul_rn(m[4], q1)), __fmul_rn(m[5], q2));
    float r2 = __fadd_rn(__fadd_rn(__fmul_rn(m[6], q0), __fmul_rn(m[7], q1)), __fmul_rn(m[8], q2));
    int b = bn / NCAM;
    for (int d = 0; d < DBIN; d++) {
        float dv = __fmul_rn((float)d + 0.5f, 2.8125f);
        float p0 = __fmul_rn(r0, dv);
        float p1 = __fmul_rn(r1, dv);
        float p2 = __fmul_rn(r2, dv);
        float px = __fadd_rn(__fadd_rn(__fadd_rn(__fmul_rn(m[12], p0), __fmul_rn(m[13], p1)), __fmul_rn(m[14], p2)), m[21]);
        float py = __fadd_rn(__fadd_rn(__fadd_rn(__fmul_rn(m[15], p0), __fmul_rn(m[16], p1)), __fmul_rn(m[17], p2)), m[22]);
        float pz = __fadd_rn(__fadd_rn(__fadd_rn(__fmul_rn(m[18], p0), __fmul_rn(m[19], p1)), __fmul_rn(m[20], p2)), m[23]);
        float fx = floorf(__fdiv_rn(__fsub_rn(px, -51.2f), 0.8f));
        float fy = floorf(__fdiv_rn(__fsub_rn(py, -51.2f), 0.8f));
        int cell = -1;
        if (fx >= 0.0f && fx < 128.0f && fy >= 0.0f && fy < 128.0f && pz >= -5.0f && pz < 3.0f)
            cell = b * (BEVH * BEVW) + (int)fy * BEVW + (int)fx;
        cellid[(bn * DBIN + d) * HW + p] = cell;
        int cprev = __shfl_up(cell, 1);
        bool leader = (lane == 0) || (cell != cprev);
        unsigned long long L = __ballot(leader);
        unsigned long long above = (lane == 63) ? 0ull : (L >> (lane + 1));
        int runlen = above ? __ffsll(above) : (64 - lane);
        if (leader && cell >= 0) atomicAdd(&counts[cell], runlen);
    }
}

// ---------------- 4. scan counts -> starts, cursors, total (single block) ---------
__global__ void lss_scan_kernel(const int* __restrict__ counts,
                                int* __restrict__ starts,
                                int* __restrict__ cursors) {
    __shared__ int sums[1024];
    int tid = threadIdx.x;
    int base = tid * 32;                 // 32768 / 1024
    int local[32];
    int s = 0;
    #pragma unroll
    for (int i = 0; i < 32; i++) { local[i] = s; s += counts[base + i]; }
    sums[tid] = s;
    __syncthreads();
    for (int off = 1; off < 1024; off <<= 1) {
        int v = 0;
        if (tid >= off) v = sums[tid - off];
        __syncthreads();
        if (tid >= off) sums[tid] += v;
        __syncthreads();
    }
    int offset = (tid > 0) ? sums[tid - 1] : 0;
    #pragma unroll
    for (int i = 0; i < 32; i++) {
        int st = offset + local[i];
        starts[base + i]  = st;
        cursors[base + i] = st;
    }
    if (tid == 1023) starts[NUMC] = sums[1023];   // total valid
}

// ---------------- 5. fill CSR (run-aggregated atomics, fused index) ---------------
__global__ void lss_fill_kernel(const int* __restrict__ cellid,
                                int* __restrict__ cursors,
                                int* __restrict__ plist,
                                int* __restrict__ pcell) {
    int i = blockIdx.x * 256 + threadIdx.x;    // NPTS = 2112*256
    int lane = threadIdx.x & 63;
    int c = cellid[i];
    int bn  = i / (DBIN * HW);
    int rem = i % (DBIN * HW);
    int d   = rem / HW;
    int p   = rem % HW;
    int pf  = ((bn * HW + p) << 4) | d;
    int cprev = __shfl_up(c, 1);
    bool leader = (lane == 0) || (c != cprev);
    unsigned long long L = __ballot(leader);
    unsigned long long above = (lane == 63) ? 0ull : (L >> (lane + 1));
    int runlen = above ? __ffsll(above) : (64 - lane);
    unsigned long long below = L & (~0ull >> (63 - lane));
    int lead = 63 - __clzll(below);
    int rank = lane - lead;
    int bse = 0;
    if (leader && c >= 0) bse = atomicAdd(&cursors[c], runlen);
    bse = __shfl(bse, lead);
    if (c >= 0) {
        plist[bse + rank] = pf;
        pcell[bse + rank] = c;
    }
}

// ---------------- 6. depthnet GEMM + softmax, c-split 4 ways ----------------------
// block: 64 pixels x 48 outs; wave w owns c in [64w, 64w+64); LDS partial reduce.
__global__ __launch_bounds__(256) void lss_gemm_kernel(const float* __restrict__ x,
                                                       const float* __restrict__ wT,
                                                       const float* __restrict__ b_dep,
                                                       float* __restrict__ yT) {
    __shared__ float part[3][64][52];          // stride 52 breaks bank alignment
    int lane = threadIdx.x & 63;
    int wv   = threadIdx.x >> 6;
    int gp   = blockIdx.x * 64 + lane;         // 528 blocks * 64 = 33792
    int ob   = blockIdx.y * 48;                // o-half
    int bn = gp / HW, p = gp % HW;
    const float* xp = x + (size_t)bn * CIN * HW + (size_t)(wv * 64) * HW + p;
    float acc[48];
    #pragma unroll
    for (int o = 0; o < 48; o++) acc[o] = 0.f;
    for (int c = 0; c < 64; c++) {
        float xv = xp[(size_t)c * HW];
        const float* wc = wT + (wv * 64 + c) * NOUT + ob;   // uniform -> s_load
        #pragma unroll
        for (int o = 0; o < 48; o++) acc[o] = fmaf(wc[o], xv, acc[o]);
    }
    if (wv) {
        #pragma unroll
        for (int o = 0; o < 48; o++) part[wv - 1][lane][o] = acc[o];
    }
    __syncthreads();
    if (wv == 0) {
        #pragma unroll
        for (int q = 0; q < 3; q++)
            #pragma unroll
            for (int o = 0; o < 48; o++) acc[o] += part[q][lane][o];
        #pragma unroll
        for (int o = 0; o < 48; o++) acc[o] += b_dep[ob + o];
        float* yp = yT + (size_t)gp * NOUT;
        if (ob == 0) {
            float m = acc[0];
            #pragma unroll
            for (int o = 1; o < 16; o++) m = fmaxf(m, acc[o]);
            float e[16], s = 0.f;
            #pragma unroll
            for (int o = 0; o < 16; o++) { e[o] = expf(acc[o] - m); s += e[o]; }
            float inv = 1.f / s;
            #pragma unroll
            for (int o = 0; o < 16; o++) yp[o] = e[o] * inv;
            #pragma unroll
            for (int o = 16; o < 48; o++) yp[o] = acc[o];
        } else {
            #pragma unroll
            for (int o = 0; o < 48; o++) yp[48 + o] = acc[o];
        }
    }
}

// ---------------- 7. chunked segmented gather -> bevHWC (atomic flush) ------------
__global__ __launch_bounds__(256) void lss_gather_kernel(const float* __restrict__ yT,
                                                         const int* __restrict__ plist,
                                                         const int* __restrict__ pcell,
                                                         const int* __restrict__ nvptr,
                                                         float* __restrict__ bevHWC) {
    int wv   = threadIdx.x >> 6;
    int lane = threadIdx.x & 63;
    int pos0 = (blockIdx.x * 4 + wv) * 64;
    int nv = *nvptr;
    if (pos0 >= nv) return;
    int n = min(64, nv - pos0);
    const int* pl = plist + pos0;
    const int* pc = pcell + pos0;
    float a0 = 0.f, a1 = 0.f;
    int cur = pc[0];
    for (int j = 0; j < n; j++) {
        int c = pc[j];                     // wave-uniform
        if (c != cur) {
            atomicAdd(&bevHWC[(size_t)cur * COUT + lane], a0);
            if (lane < 16) atomicAdd(&bevHWC[(size_t)cur * COUT + 64 + lane], a1);
            a0 = a1 = 0.f;
            cur = c;
        }
        int pf = pl[j];
        const float* yp = yT + (size_t)(pf >> 4) * NOUT;
        float dep = yp[pf & 15];
        a0 = fmaf(dep, yp[16 + lane], a0);
        if (lane < 16) a1 = fmaf(dep, yp[80 + lane], a1);
    }
    atomicAdd(&bevHWC[(size_t)cur * COUT + lane], a0);
    if (lane < 16) atomicAdd(&bevHWC[(size_t)cur * COUT + 64 + lane], a1);
}

// ---------------- 8. transpose HWC->CHW + normalize by count ----------------------
__global__ __launch_bounds__(256) void lss_tr_kernel(const float* __restrict__ bevHWC,
                                                     const int* __restrict__ counts,
                                                     float* __restrict__ bevCHW) {
    __shared__ float t[COUT][65];
    __shared__ float ic[64];
    int tid = threadIdx.x;
    int cellbase = blockIdx.x * 64;
    if (tid < 64) {
        int cnt = counts[cellbase + tid];
        ic[tid] = 1.f / fmaxf((float)cnt, 1.f);
    }
    const float* src = bevHWC + (size_t)cellbase * COUT;
    #pragma unroll
    for (int k = 0; k < 20; k++) {
        int idx = tid + k * 256;           // 5120 = 20*256
        int yx = idx / COUT, ch = idx % COUT;
        t[ch][yx] = src[idx];
    }
    __syncthreads();
    int b  = cellbase >> 14;
    int yx0 = cellbase & 16383;
    #pragma unroll
    for (int k = 0; k < 20; k++) {
        int idx = tid + k * 256;
        int ch = idx / 64, yxl = idx % 64;
        bevCHW[((size_t)(b * COUT + ch)) * (BEVH * BEVW) + yx0 + yxl] = t[ch][yxl] * ic[yxl];
    }
}

// ---------------- 9. 3x3 SAME conv — barrier-free register-window streaming -------
// block: 256 thr = 128 cols x 2 row-groups (2 rows each) = 4 out rows; og-group 8.
// thread: 1 col x 2 rows x 8 och; 4x3 window, 12 const-offset L2 loads per ci,
// 144 FMA per ci. No LDS, no barriers, no divisions.
__global__ __launch_bounds__(256) void lss_conv_kernel(const float* __restrict__ bev,
                                                       const float* __restrict__ w,
                                                       const float* __restrict__ bias,
                                                       float* __restrict__ out) {
    int bx = blockIdx.x;               // 0..63 = b*32 + ytile
    int og = blockIdx.y * 8;           // 10 groups
    int b  = bx >> 5;
    int y0 = (bx & 31) * 4;
    int x  = threadIdx.x & 127;
    int rg = threadIdx.x >> 7;         // 0 or 1
    int yb = y0 + rg * 2;              // first out row of this thread

    int offs[4][3];
    float msk[4][3];
    #pragma unroll
    for (int r = 0; r < 4; r++) {
        int yy = yb + r - 1;
        float ym = (yy >= 0 && yy < 128) ? 1.f : 0.f;
        int yc = min(max(yy, 0), 127);
        #pragma unroll
        for (int c = 0; c < 3; c++) {
            int xx = x + c - 1;
            float xm = (xx >= 0 && xx < 128) ? 1.f : 0.f;
            int xc = min(max(xx, 0), 127);
            offs[r][c] = yc * BEVW + xc;
            msk[r][c]  = ym * xm;
        }
    }

    float acc[8][2];
    #pragma unroll
    for (int o = 0; o < 8; o++) { acc[o][0] = 0.f; acc[o][1] = 0.f; }

    const float* pb = bev + (size_t)b * COUT * (BEVH * BEVW);
    for (int ci = 0; ci < COUT; ci++) {
        const float* pc = pb + (size_t)ci * (BEVH * BEVW);
        float win[4][3];
        #pragma unroll
        for (int r = 0; r < 4; r++)
            #pragma unroll
            for (int c = 0; c < 3; c++)
                win[r][c] = pc[offs[r][c]] * msk[r][c];
        #pragma unroll
        for (int o = 0; o < 8; o++) {
            const float* wp = w + ((size_t)(og + o) * COUT + ci) * 9;   // uniform -> s_load
            #pragma unroll
            for (int j = 0; j < 2; j++) {
                float a = acc[o][j];
                a = fmaf(wp[0], win[j][0],     a);
                a = fmaf(wp[1], win[j][1],     a);
                a = fmaf(wp[2], win[j][2],     a);
                a = fmaf(wp[3], win[j + 1][0], a);
                a = fmaf(wp[4], win[j + 1][1], a);
                a = fmaf(wp[5], win[j + 1][2], a);
                a = fmaf(wp[6], win[j + 2][0], a);
                a = fmaf(wp[7], win[j + 2][1], a);
                a = fmaf(wp[8], win[j + 2][2], a);
                acc[o][j] = a;
            }
        }
    }
    #pragma unroll
    for (int o = 0; o < 8; o++) {
        float bi = bias[og + o];
        #pragma unroll
        for (int j = 0; j < 2; j++)
            out[((size_t)(b * COUT + og + o) * BEVH + (yb + j)) * BEVW + x] = acc[o][j] + bi;
    }
}

// ---------------- launch ----------------
extern "C" void kernel_launch(void* const* d_in, const int* in_sizes, int n_in,
                              void* d_out, int out_size, void* d_ws, size_t ws_size,
                              hipStream_t stream) {
    (void)in_sizes; (void)n_in; (void)out_size; (void)ws_size;
    const float* x     = (const float*)d_in[0];
    const float* l2i   = (const float*)d_in[1];
    const float* aug   = (const float*)d_in[2];
    const float* w_dep = (const float*)d_in[3];
    const float* b_dep = (const float*)d_in[4];
    const float* w_ref = (const float*)d_in[5];
    const float* b_ref = (const float*)d_in[6];
    float* out = (float*)d_out;

    char* ws = (char*)d_ws;
    float* mats    = (float*)(ws + MATS_OFF);
    float* wT      = (float*)(ws + WT_OFF);
    float* yT      = (float*)(ws + YT_OFF);     // reused as bevCHW after gather
    float* bevCHW  = (float*)(ws + YT_OFF);
    int*   cellid  = (int*)(ws + CELL_OFF);
    int*   counts  = (int*)(ws + COUNTS_OFF);
    int*   starts  = (int*)(ws + STARTS_OFF);
    int*   cursors = (int*)(ws + CURS_OFF);
    int*   plist   = (int*)(ws + PLIST_OFF);
    int*   pcell   = (int*)(ws + PCELL_OFF);
    float* bevHWC  = (float*)(ws + BEVHWC_OFF);

    hipMemsetAsync(counts, 0, NUMC * sizeof(int), stream);
    hipMemsetAsync(bevHWC, 0, (size_t)NUMC * COUT * sizeof(float), stream);
    lss_prep_kernel<<<1, 64, 0, stream>>>(l2i, aug, mats);
    lss_wt_kernel<<<96, 256, 0, stream>>>(w_dep, wT);
    lss_geom_kernel<<<BN * HW / 256, 256, 0, stream>>>(mats, cellid, counts);
    lss_scan_kernel<<<1, 1024, 0, stream>>>(counts, starts, cursors);
    lss_fill_kernel<<<NPTS / 256, 256, 0, stream>>>(cellid, cursors, plist, pcell);
    lss_gemm_kernel<<<dim3(528, 2), 256, 0, stream>>>(x, wT, b_dep, yT);
    lss_gather_kernel<<<NPTS / 256, 256, 0, stream>>>(yT, plist, pcell, starts + NUMC, bevHWC);
    lss_tr_kernel<<<NUMC / 64, 256, 0, stream>>>(bevHWC, counts, bevCHW);
    lss_conv_kernel<<<dim3(64, 10), 256, 0, stream>>>(bevCHW, w_ref, b_ref, out);
}